// Round 1
// baseline (647.937 us; speedup 1.0000x reference)
//
#include <hip/hip_runtime.h>

typedef __attribute__((ext_vector_type(8))) __bf16 bf16x8;
typedef __attribute__((ext_vector_type(4))) float f32x4;
typedef __attribute__((ext_vector_type(8))) unsigned short u16x8;
typedef __attribute__((ext_vector_type(4))) unsigned short u16x4;

// f32 -> bf16 bits, round-to-nearest-even
__device__ __forceinline__ unsigned short f2b(float f) {
    union { float f; unsigned u; } v; v.f = f;
    unsigned r = v.u + 0x7fffu + ((v.u >> 16) & 1u);
    return (unsigned short)(r >> 16);
}

__device__ __forceinline__ bf16x8 ld_frag(const unsigned short* p) {
    u16x8 v = *(const u16x8*)p;
    return __builtin_bit_cast(bf16x8, v);
}

// block-wide sum of s and q across 256 threads (4 waves), deterministic
__device__ __forceinline__ void block_reduce2(float& s, float& q, float* red) {
    for (int m = 1; m < 64; m <<= 1) { s += __shfl_xor(s, m); q += __shfl_xor(q, m); }
    int w = threadIdx.x >> 6;
    __syncthreads();
    if ((threadIdx.x & 63) == 0) { red[w] = s; red[w + 4] = q; }
    __syncthreads();
    s = red[0] + red[1] + red[2] + red[3];
    q = red[4] + red[5] + red[6] + red[7];
}

// ---------------- GEMM1: params[CH,32768] = query[q0+CH,256] @ Wp^T + (bp later) ----
// 128x128 tile, BK=32, 4 waves each 64x64. Output bf16 into pm.
__global__ __launch_bounds__(256) void k_gemm1(
    const float* __restrict__ query, const float* __restrict__ Wp,
    const float* __restrict__ bp, unsigned short* __restrict__ pm,
    int q0, int CH)
{
    __shared__ unsigned short As[128 * 40];
    __shared__ unsigned short Bs[128 * 40];
    const int t = threadIdx.x;
    const int lane = t & 63, w = t >> 6;
    const int l15 = lane & 15, k8 = lane >> 4;
    const int n0 = blockIdx.x * 128;
    const int m0c = blockIdx.y * 128;
    const int wm = (w >> 1) * 64, wn = (w & 1) * 64;

    f32x4 acc[4][4];
    for (int i = 0; i < 4; ++i)
        for (int j = 0; j < 4; ++j) acc[i][j] = (f32x4){0.f, 0.f, 0.f, 0.f};

    const int ar = t >> 3, ac4 = t & 7;
    for (int kt = 0; kt < 8; ++kt) {
        const int k0 = kt * 32;
        __syncthreads();
        for (int i = 0; i < 4; ++i) {
            int r = ar + 32 * i;
            int cm = m0c + r; if (cm > CH - 1) cm = CH - 1;
            f32x4 v = *(const f32x4*)&query[(size_t)(q0 + cm) * 256 + k0 + ac4 * 4];
            u16x4 o = { f2b(v[0]), f2b(v[1]), f2b(v[2]), f2b(v[3]) };
            *(u16x4*)&As[r * 40 + ac4 * 4] = o;
            f32x4 wv = *(const f32x4*)&Wp[(size_t)(n0 + r) * 256 + k0 + ac4 * 4];
            u16x4 ob = { f2b(wv[0]), f2b(wv[1]), f2b(wv[2]), f2b(wv[3]) };
            *(u16x4*)&Bs[r * 40 + ac4 * 4] = ob;
        }
        __syncthreads();
        bf16x8 a[4], b[4];
        for (int mi = 0; mi < 4; ++mi) a[mi] = ld_frag(&As[(wm + mi * 16 + l15) * 40 + k8 * 8]);
        for (int ni = 0; ni < 4; ++ni) b[ni] = ld_frag(&Bs[(wn + ni * 16 + l15) * 40 + k8 * 8]);
        for (int mi = 0; mi < 4; ++mi)
            for (int ni = 0; ni < 4; ++ni)
                acc[mi][ni] = __builtin_amdgcn_mfma_f32_16x16x32_bf16(a[mi], b[ni], acc[mi][ni], 0, 0, 0);
    }
    for (int ni = 0; ni < 4; ++ni) {
        float bpv = bp[n0 + wn + ni * 16 + l15];
        for (int mi = 0; mi < 4; ++mi)
            for (int r = 0; r < 4; ++r) {
                int row = wm + mi * 16 + k8 * 4 + r;
                int cm = m0c + row;
                if (cm < CH)
                    pm[(size_t)cm * 32768 + n0 + wn + ni * 16 + l15] = f2b(acc[mi][ni][r] + bpv);
            }
    }
}

// ---------------- MIX: per (g, n) workgroup. In-place params->mid. ------------------
__global__ __launch_bounds__(256) void k_mix(
    const float* __restrict__ x, unsigned short* __restrict__ pm, int q0, int CH)
{
    __shared__ unsigned short Mt[64 * 72];  // M transposed: [d][c]
    __shared__ unsigned short Ax[32 * 72];  // x tile: [p][c]
    __shared__ unsigned short Ss[128 * 40]; // S: [o][p]
    __shared__ unsigned short O1[64 * 40];  // out1 transposed: [d][p]
    __shared__ float red[8];
    const int t = threadIdx.x, lane = t & 63, w = t >> 6;
    const int l15 = lane & 15, k8 = lane >> 4;
    const int g = blockIdx.x, nq = blockIdx.y;
    const int q = q0 + nq;
    unsigned short* pmq = pm + (size_t)nq * 32768 + g * 8192;
    const float* xg = x + (size_t)(q * 4 + g) * 2048;

    { // stage M transposed
        int c = t >> 2, d0 = (t & 3) * 16;
        for (int i = 0; i < 4; ++i) {
            u16x4 v = *(const u16x4*)&pmq[c * 64 + d0 + i * 4];
            Mt[(d0 + i * 4 + 0) * 72 + c] = v[0];
            Mt[(d0 + i * 4 + 1) * 72 + c] = v[1];
            Mt[(d0 + i * 4 + 2) * 72 + c] = v[2];
            Mt[(d0 + i * 4 + 3) * 72 + c] = v[3];
        }
    }
    { // stage x (f32 -> bf16)
        int p = t >> 4, c0 = (t & 15) * 4;
        for (int i = 0; i < 2; ++i) {
            int pp = p + 16 * i;
            f32x4 v = *(const f32x4*)&xg[pp * 64 + c0];
            u16x4 o = { f2b(v[0]), f2b(v[1]), f2b(v[2]), f2b(v[3]) };
            *(u16x4*)&Ax[pp * 72 + c0] = o;
        }
    }
    { // stage S
        int o = t >> 1, p0 = (t & 1) * 16;
        for (int i = 0; i < 4; ++i) {
            u16x4 v = *(const u16x4*)&pmq[4096 + o * 32 + p0 + i * 4];
            *(u16x4*)&Ss[o * 40 + p0 + i * 4] = v;
        }
    }
    __syncthreads();

    // out1 = x @ M : 32x64, K=64. Wave w owns d-quad [16w,16w+16).
    f32x4 acc1[2] = { (f32x4){0.f,0.f,0.f,0.f}, (f32x4){0.f,0.f,0.f,0.f} };
    for (int kk = 0; kk < 2; ++kk) {
        bf16x8 b = ld_frag(&Mt[(16 * w + l15) * 72 + kk * 32 + k8 * 8]);
        for (int mi = 0; mi < 2; ++mi) {
            bf16x8 a = ld_frag(&Ax[(mi * 16 + l15) * 72 + kk * 32 + k8 * 8]);
            acc1[mi] = __builtin_amdgcn_mfma_f32_16x16x32_bf16(a, b, acc1[mi], 0, 0, 0);
        }
    }
    // LN over 32x64 + relu, store transposed to O1
    float s = 0.f, sq = 0.f;
    for (int mi = 0; mi < 2; ++mi)
        for (int r = 0; r < 4; ++r) { float v = acc1[mi][r]; s += v; sq += v * v; }
    block_reduce2(s, sq, red);
    float mean = s * (1.f / 2048.f);
    float inv = rsqrtf(sq * (1.f / 2048.f) - mean * mean + 1e-5f);
    for (int mi = 0; mi < 2; ++mi)
        for (int r = 0; r < 4; ++r) {
            float v = (acc1[mi][r] - mean) * inv; v = fmaxf(v, 0.f);
            int p = mi * 16 + k8 * 4 + r, d = 16 * w + l15;
            O1[d * 40 + p] = f2b(v);
        }
    __syncthreads();

    // out2 = S @ out1 : 128x64, K=32. Wave w owns d-quad.
    f32x4 acc2[8];
    for (int mi = 0; mi < 8; ++mi) acc2[mi] = (f32x4){0.f, 0.f, 0.f, 0.f};
    bf16x8 b2 = ld_frag(&O1[(16 * w + l15) * 40 + k8 * 8]);
    for (int mi = 0; mi < 8; ++mi) {
        bf16x8 a2 = ld_frag(&Ss[(mi * 16 + l15) * 40 + k8 * 8]);
        acc2[mi] = __builtin_amdgcn_mfma_f32_16x16x32_bf16(a2, b2, acc2[mi], 0, 0, 0);
    }
    // LN over 128x64 + relu, write mid (in place over params slice)
    s = 0.f; sq = 0.f;
    for (int mi = 0; mi < 8; ++mi)
        for (int r = 0; r < 4; ++r) { float v = acc2[mi][r]; s += v; sq += v * v; }
    block_reduce2(s, sq, red);
    mean = s * (1.f / 8192.f);
    inv = rsqrtf(sq * (1.f / 8192.f) - mean * mean + 1e-5f);
    for (int mi = 0; mi < 8; ++mi)
        for (int r = 0; r < 4; ++r) {
            float v = (acc2[mi][r] - mean) * inv; v = fmaxf(v, 0.f);
            int o = mi * 16 + k8 * 4 + r, d = 16 * w + l15;
            pmq[o * 64 + d] = f2b(v);
        }
}

// ---------------- GEMM2: part[ks,CH,256] = mid[CH, kslice] @ Wo[:, kslice]^T --------
// BM=64, BN=256 (full), split-K=16, 4 waves each 64x64.
__global__ __launch_bounds__(256) void k_gemm2(
    const unsigned short* __restrict__ pm, const float* __restrict__ Wo,
    float* __restrict__ part, int CH)
{
    __shared__ unsigned short As[64 * 40];
    __shared__ unsigned short Bs[256 * 40];
    const int t = threadIdx.x, lane = t & 63, w = t >> 6;
    const int l15 = lane & 15, k8 = lane >> 4;
    const int ks = blockIdx.x;
    const int m0 = blockIdx.y * 64;
    const int kbase = ks * 2048;

    f32x4 acc[4][4];
    for (int i = 0; i < 4; ++i)
        for (int j = 0; j < 4; ++j) acc[i][j] = (f32x4){0.f, 0.f, 0.f, 0.f};

    const int arr = t >> 2, akq = t & 3;
    const int br = t >> 3, bc4 = t & 7;
    for (int kt = 0; kt < 64; ++kt) {
        const int k = kbase + kt * 32;
        __syncthreads();
        {
            int cm = m0 + arr; if (cm > CH - 1) cm = CH - 1;
            u16x8 v = *(const u16x8*)&pm[(size_t)cm * 32768 + k + akq * 8];
            *(u16x8*)&As[arr * 40 + akq * 8] = v;
        }
        for (int i = 0; i < 8; ++i) {
            int d = br + 32 * i;
            f32x4 v = *(const f32x4*)&Wo[(size_t)d * 32768 + k + bc4 * 4];
            u16x4 o = { f2b(v[0]), f2b(v[1]), f2b(v[2]), f2b(v[3]) };
            *(u16x4*)&Bs[d * 40 + bc4 * 4] = o;
        }
        __syncthreads();
        bf16x8 a[4], b[4];
        for (int mi = 0; mi < 4; ++mi) a[mi] = ld_frag(&As[(mi * 16 + l15) * 40 + k8 * 8]);
        for (int ni = 0; ni < 4; ++ni) b[ni] = ld_frag(&Bs[(64 * w + ni * 16 + l15) * 40 + k8 * 8]);
        for (int mi = 0; mi < 4; ++mi)
            for (int ni = 0; ni < 4; ++ni)
                acc[mi][ni] = __builtin_amdgcn_mfma_f32_16x16x32_bf16(a[mi], b[ni], acc[mi][ni], 0, 0, 0);
    }
    for (int mi = 0; mi < 4; ++mi)
        for (int ni = 0; ni < 4; ++ni)
            for (int r = 0; r < 4; ++r) {
                int row = mi * 16 + k8 * 4 + r;
                int cm = m0 + row;
                int d = 64 * w + ni * 16 + l15;
                if (cm < CH) part[((size_t)ks * CH + cm) * 256 + d] = acc[mi][ni][r];
            }
}

// ---------------- REDUCE: out = query + bo + sum_ks part ---------------------------
__global__ __launch_bounds__(256) void k_reduce(
    const float* __restrict__ part, const float* __restrict__ query,
    const float* __restrict__ bo, float* __restrict__ out, int q0, int CH)
{
    int row = blockIdx.x, d = threadIdx.x;
    float s = bo[d] + query[(size_t)(q0 + row) * 256 + d];
    for (int ks = 0; ks < 16; ++ks) s += part[((size_t)ks * CH + row) * 256 + d];
    out[(size_t)(q0 + row) * 256 + d] = s;
}

extern "C" void kernel_launch(void* const* d_in, const int* in_sizes, int n_in,
                              void* d_out, int out_size, void* d_ws, size_t ws_size,
                              hipStream_t stream) {
    const float* x     = (const float*)d_in[0];
    const float* query = (const float*)d_in[1];
    const float* Wp    = (const float*)d_in[2];
    const float* bp    = (const float*)d_in[3];
    const float* Wo    = (const float*)d_in[4];
    const float* bo    = (const float*)d_in[5];
    float* out = (float*)d_out;

    // pick largest chunk that fits workspace: pm (CH*32768 bf16) + part (16*CH*256 f32)
    static const int cands[] = {4000, 2000, 1000, 500, 250, 200, 125, 100, 50, 40, 25, 20, 10, 8, 5, 4, 2, 1};
    int CH = 1;
    for (int i = 0; i < (int)(sizeof(cands) / sizeof(cands[0])); ++i) {
        size_t need = (size_t)cands[i] * 32768 * 2 + (size_t)16 * cands[i] * 256 * 4;
        if (need <= ws_size) { CH = cands[i]; break; }
    }
    unsigned short* pm = (unsigned short*)d_ws;
    float* part = (float*)((char*)d_ws + (size_t)CH * 32768 * 2);
    const int NC = 4000 / CH;

    for (int c = 0; c < NC; ++c) {
        int q0 = c * CH;
        k_gemm1<<<dim3(256, (CH + 127) / 128), 256, 0, stream>>>(query, Wp, bp, pm, q0, CH);
        k_mix<<<dim3(4, CH), 256, 0, stream>>>(x, pm, q0, CH);
        k_gemm2<<<dim3(16, (CH + 63) / 64), 256, 0, stream>>>(pm, Wo, part, CH);
        k_reduce<<<dim3(CH), 256, 0, stream>>>(part, query, bo, out, q0, CH);
    }
}

// Round 2
// 439.177 us; speedup vs baseline: 1.4753x; 1.4753x over previous
//
#include <hip/hip_runtime.h>

typedef __attribute__((ext_vector_type(8))) __bf16 bf16x8;
typedef __attribute__((ext_vector_type(4))) float f32x4;
typedef __attribute__((ext_vector_type(8))) unsigned short u16x8;
typedef __attribute__((ext_vector_type(4))) unsigned short u16x4;
typedef unsigned int u32;

// f32 -> bf16 bits, round-to-nearest-even
__device__ __forceinline__ unsigned short f2b(float f) {
    union { float f; unsigned u; } v; v.f = f;
    unsigned r = v.u + 0x7fffu + ((v.u >> 16) & 1u);
    return (unsigned short)(r >> 16);
}

__device__ __forceinline__ bf16x8 ld_frag(const unsigned short* p) {
    u16x8 v = *(const u16x8*)p;
    return __builtin_bit_cast(bf16x8, v);
}

// async 16B global -> LDS (linear dest: wave base + lane*16)
__device__ __forceinline__ void gl16(void* lds, const void* g) {
    __builtin_amdgcn_global_load_lds(
        (const __attribute__((address_space(1))) u32*)g,
        (__attribute__((address_space(3))) u32*)lds, 16, 0, 0);
}

// params-column permutation: pm col j holds original param index inv(j)
// (M block stored transposed so the mix kernel needs no LDS transpose)
__device__ __forceinline__ int inv_col(int j) {
    int off = j & 8191;
    return (off < 4096) ? ((j & ~8191) | ((off & 63) << 6) | (off >> 6)) : j;
}

// block-wide sum of s and q across 256 threads (4 waves), deterministic
__device__ __forceinline__ void block_reduce2(float& s, float& q, float* red) {
    for (int m = 1; m < 64; m <<= 1) { s += __shfl_xor(s, m); q += __shfl_xor(q, m); }
    int w = threadIdx.x >> 6;
    __syncthreads();
    if ((threadIdx.x & 63) == 0) { red[w] = s; red[w + 4] = q; }
    __syncthreads();
    s = red[0] + red[1] + red[2] + red[3];
    q = red[4] + red[5] + red[6] + red[7];
}

// ---------------- conversion kernels -----------------------------------------------
__global__ __launch_bounds__(256) void k_cvt(const float* __restrict__ src,
                                             unsigned short* __restrict__ dst, int n4) {
    int i = blockIdx.x * 256 + threadIdx.x;
    int stride = gridDim.x * 256;
    for (; i < n4; i += stride) {
        f32x4 v = *(const f32x4*)&src[(size_t)i * 4];
        u16x4 o = { f2b(v[0]), f2b(v[1]), f2b(v[2]), f2b(v[3]) };
        *(u16x4*)&dst[(size_t)i * 4] = o;
    }
}

__global__ __launch_bounds__(256) void k_cvt_wp(const float* __restrict__ Wp,
                                                unsigned short* __restrict__ Wpb, int n4) {
    int i = blockIdx.x * 256 + threadIdx.x;
    int stride = gridDim.x * 256;
    for (; i < n4; i += stride) {
        int e = i * 4;
        int j = e >> 8, k = e & 255;
        int jo = inv_col(j);
        f32x4 v = *(const f32x4*)&Wp[(size_t)jo * 256 + k];
        u16x4 o = { f2b(v[0]), f2b(v[1]), f2b(v[2]), f2b(v[3]) };
        *(u16x4*)&Wpb[(size_t)e] = o;
    }
}

__global__ __launch_bounds__(256) void k_perm_bp(const float* __restrict__ bp,
                                                 float* __restrict__ bpp) {
    int j = blockIdx.x * 256 + threadIdx.x;
    bpp[j] = bp[inv_col(j)];
}

// ---------------- GEMM1: pm[CH,32768] = qb @ Wpb^T + bpp (bf16 out) ----------------
// 128x128 tile, BK=32, 4 waves 64x64, global_load_lds staging, LDS-repacked store.
__global__ __launch_bounds__(256) void k_gemm1(
    const unsigned short* __restrict__ qb, const unsigned short* __restrict__ Wpb,
    const float* __restrict__ bpp, unsigned short* __restrict__ pm, int CH)
{
    __shared__ unsigned short As[128 * 32];
    __shared__ unsigned short Bs[128 * 32];
    __shared__ unsigned short Ep[128 * 128];
    const int t = threadIdx.x, lane = t & 63, w = t >> 6;
    const int l15 = lane & 15, k8 = lane >> 4;
    const int n0 = blockIdx.x * 128, m0 = blockIdx.y * 128;
    const int wm = (w >> 1) * 64, wn = (w & 1) * 64;

    f32x4 acc[4][4];
    for (int i = 0; i < 4; ++i)
        for (int j = 0; j < 4; ++j) acc[i][j] = (f32x4){0.f, 0.f, 0.f, 0.f};

    const int off0 = t * 16, off1 = t * 16 + 4096;
    const int ra0 = off0 >> 6, ca0 = off0 & 63;
    const int ra1 = off1 >> 6, ca1 = off1 & 63;
    int ma0 = m0 + ra0; if (ma0 >= CH) ma0 = CH - 1;
    int ma1 = m0 + ra1; if (ma1 >= CH) ma1 = CH - 1;
    const char* qbase = (const char*)qb;
    const char* wbase = (const char*)Wpb;

    for (int kt = 0; kt < 8; ++kt) {
        const int kb = kt * 64;
        __syncthreads();
        gl16((char*)As + off0, qbase + (size_t)ma0 * 512 + kb + ca0);
        gl16((char*)As + off1, qbase + (size_t)ma1 * 512 + kb + ca1);
        gl16((char*)Bs + off0, wbase + (size_t)(n0 + ra0) * 512 + kb + ca0);
        gl16((char*)Bs + off1, wbase + (size_t)(n0 + ra1) * 512 + kb + ca1);
        __syncthreads();
        bf16x8 a[4], b[4];
        for (int mi = 0; mi < 4; ++mi) a[mi] = ld_frag(&As[(wm + mi * 16 + l15) * 32 + k8 * 8]);
        for (int ni = 0; ni < 4; ++ni) b[ni] = ld_frag(&Bs[(wn + ni * 16 + l15) * 32 + k8 * 8]);
        for (int mi = 0; mi < 4; ++mi)
            for (int ni = 0; ni < 4; ++ni)
                acc[mi][ni] = __builtin_amdgcn_mfma_f32_16x16x32_bf16(a[mi], b[ni], acc[mi][ni], 0, 0, 0);
    }
    // bias + pack into Ep
    for (int ni = 0; ni < 4; ++ni) {
        int col = wn + ni * 16 + l15;
        float bpv = bpp[n0 + col];
        for (int mi = 0; mi < 4; ++mi)
            for (int r = 0; r < 4; ++r) {
                int row = wm + mi * 16 + k8 * 4 + r;
                Ep[row * 128 + col] = f2b(acc[mi][ni][r] + bpv);
            }
    }
    __syncthreads();
    // coalesced store: each thread 8 x 16B
    for (int i = 0; i < 8; ++i) {
        int off = t * 16 + i * 4096;
        int row = off >> 8, colb = off & 255;
        int cm = m0 + row;
        if (cm < CH)
            *(u16x8*)((char*)pm + (size_t)cm * 65536 + (size_t)n0 * 2 + colb) =
                *(const u16x8*)((const char*)Ep + off);
    }
}

// ---------------- MIX: per (g, nq) block; in-place params->mid ---------------------
__global__ __launch_bounds__(256) void k_mix(
    const float* __restrict__ x, unsigned short* __restrict__ pm, int q0)
{
    __shared__ char SB[29184];      // MtP | Ax | Ss | O1 ; O2 aliases front 16KB
    __shared__ float red[8];
    unsigned short* MtP = (unsigned short*)SB;             // [64][72]  M^T
    unsigned short* Ax  = (unsigned short*)(SB + 9216);    // [32][72]
    unsigned short* Ss  = (unsigned short*)(SB + 13824);   // [128][40]
    unsigned short* O1  = (unsigned short*)(SB + 24064);   // [64][40]  out1^T
    unsigned short* O2  = (unsigned short*)SB;             // [128][64] final, aliased
    const int t = threadIdx.x, lane = t & 63, w = t >> 6;
    const int l15 = lane & 15, k8 = lane >> 4;
    const int g = blockIdx.x, nq = blockIdx.y;
    unsigned short* pmq = pm + (size_t)nq * 32768 + g * 8192;
    const float* xg = x + ((size_t)(q0 + nq) * 4 + g) * 2048;

    { // stage M^T (already transposed by Wp permutation)
        int d = t >> 2, c0 = (t & 3) * 16;
        u16x8 v0 = *(const u16x8*)&pmq[d * 64 + c0];
        u16x8 v1 = *(const u16x8*)&pmq[d * 64 + c0 + 8];
        *(u16x8*)&MtP[d * 72 + c0] = v0;
        *(u16x8*)&MtP[d * 72 + c0 + 8] = v1;
    }
    { // stage S
        int o = t >> 1, p0 = (t & 1) * 16;
        u16x8 v0 = *(const u16x8*)&pmq[4096 + o * 32 + p0];
        u16x8 v1 = *(const u16x8*)&pmq[4096 + o * 32 + p0 + 8];
        *(u16x8*)&Ss[o * 40 + p0] = v0;
        *(u16x8*)&Ss[o * 40 + p0 + 8] = v1;
    }
    { // stage x (f32 -> bf16)
        int p = t >> 3, c0 = (t & 7) * 8;
        f32x4 v0 = *(const f32x4*)&xg[p * 64 + c0];
        f32x4 v1 = *(const f32x4*)&xg[p * 64 + c0 + 4];
        u16x8 o8 = { f2b(v0[0]), f2b(v0[1]), f2b(v0[2]), f2b(v0[3]),
                     f2b(v1[0]), f2b(v1[1]), f2b(v1[2]), f2b(v1[3]) };
        *(u16x8*)&Ax[p * 72 + c0] = o8;
    }
    __syncthreads();

    // out1 = x @ M : 32x64, K=64. Wave w owns cols 16w..16w+15.
    f32x4 acc1[2] = { (f32x4){0.f,0.f,0.f,0.f}, (f32x4){0.f,0.f,0.f,0.f} };
    for (int kk = 0; kk < 2; ++kk) {
        bf16x8 b = ld_frag(&MtP[(16 * w + l15) * 72 + kk * 32 + k8 * 8]);
        for (int mi = 0; mi < 2; ++mi) {
            bf16x8 a = ld_frag(&Ax[(mi * 16 + l15) * 72 + kk * 32 + k8 * 8]);
            acc1[mi] = __builtin_amdgcn_mfma_f32_16x16x32_bf16(a, b, acc1[mi], 0, 0, 0);
        }
    }
    float s = 0.f, sq = 0.f;
    for (int mi = 0; mi < 2; ++mi)
        for (int r = 0; r < 4; ++r) { float v = acc1[mi][r]; s += v; sq += v * v; }
    block_reduce2(s, sq, red);
    float mean = s * (1.f / 2048.f);
    float inv = rsqrtf(sq * (1.f / 2048.f) - mean * mean + 1e-5f);
    for (int mi = 0; mi < 2; ++mi)
        for (int r = 0; r < 4; ++r) {
            float v = (acc1[mi][r] - mean) * inv; v = fmaxf(v, 0.f);
            int p = mi * 16 + k8 * 4 + r, d = 16 * w + l15;
            O1[d * 40 + p] = f2b(v);
        }
    __syncthreads();

    // out2 = S @ out1 : 128x64, K=32
    f32x4 acc2[8];
    for (int mi = 0; mi < 8; ++mi) acc2[mi] = (f32x4){0.f, 0.f, 0.f, 0.f};
    bf16x8 b2 = ld_frag(&O1[(16 * w + l15) * 40 + k8 * 8]);
    for (int mi = 0; mi < 8; ++mi) {
        bf16x8 a2 = ld_frag(&Ss[(mi * 16 + l15) * 40 + k8 * 8]);
        acc2[mi] = __builtin_amdgcn_mfma_f32_16x16x32_bf16(a2, b2, acc2[mi], 0, 0, 0);
    }
    s = 0.f; sq = 0.f;
    for (int mi = 0; mi < 8; ++mi)
        for (int r = 0; r < 4; ++r) { float v = acc2[mi][r]; s += v; sq += v * v; }
    block_reduce2(s, sq, red);   // contains barriers -> safe to alias O2 after
    mean = s * (1.f / 8192.f);
    inv = rsqrtf(sq * (1.f / 8192.f) - mean * mean + 1e-5f);
    for (int mi = 0; mi < 8; ++mi)
        for (int r = 0; r < 4; ++r) {
            float v = (acc2[mi][r] - mean) * inv; v = fmaxf(v, 0.f);
            int o = mi * 16 + k8 * 4 + r, d = 16 * w + l15;
            O2[o * 64 + d] = f2b(v);
        }
    __syncthreads();
    // coalesced write-back: 16KB contiguous
    for (int i = 0; i < 4; ++i) {
        int off = t * 16 + i * 4096;
        *(u16x8*)((char*)pmq + off) = *(const u16x8*)((const char*)O2 + off);
    }
}

// ---------------- GEMM2: part[ks,CH,256] = pm @ Wob^T (split-K 8) ------------------
// BM=128, BN=128, BK=32, 4 waves 64x64.
__global__ __launch_bounds__(256) void k_gemm2(
    const unsigned short* __restrict__ pm, const unsigned short* __restrict__ Wob,
    float* __restrict__ part, int CH)
{
    __shared__ unsigned short As[128 * 32];
    __shared__ unsigned short Bs[128 * 32];
    const int t = threadIdx.x, lane = t & 63, w = t >> 6;
    const int l15 = lane & 15, k8 = lane >> 4;
    const int n0 = blockIdx.x * 128, m0 = blockIdx.y * 128, ks = blockIdx.z;
    const int wm = (w >> 1) * 64, wn = (w & 1) * 64;

    f32x4 acc[4][4];
    for (int i = 0; i < 4; ++i)
        for (int j = 0; j < 4; ++j) acc[i][j] = (f32x4){0.f, 0.f, 0.f, 0.f};

    const int off0 = t * 16, off1 = t * 16 + 4096;
    const int ra0 = off0 >> 6, ca0 = off0 & 63;
    const int ra1 = off1 >> 6, ca1 = off1 & 63;
    int ma0 = m0 + ra0; if (ma0 >= CH) ma0 = CH - 1;
    int ma1 = m0 + ra1; if (ma1 >= CH) ma1 = CH - 1;
    const char* abase = (const char*)pm;
    const char* bbase = (const char*)Wob;

    for (int kt = 0; kt < 128; ++kt) {
        const int kb = ks * 8192 + kt * 64;
        __syncthreads();
        gl16((char*)As + off0, abase + (size_t)ma0 * 65536 + kb + ca0);
        gl16((char*)As + off1, abase + (size_t)ma1 * 65536 + kb + ca1);
        gl16((char*)Bs + off0, bbase + (size_t)(n0 + ra0) * 65536 + kb + ca0);
        gl16((char*)Bs + off1, bbase + (size_t)(n0 + ra1) * 65536 + kb + ca1);
        __syncthreads();
        bf16x8 a[4], b[4];
        for (int mi = 0; mi < 4; ++mi) a[mi] = ld_frag(&As[(wm + mi * 16 + l15) * 32 + k8 * 8]);
        for (int ni = 0; ni < 4; ++ni) b[ni] = ld_frag(&Bs[(wn + ni * 16 + l15) * 32 + k8 * 8]);
        for (int mi = 0; mi < 4; ++mi)
            for (int ni = 0; ni < 4; ++ni)
                acc[mi][ni] = __builtin_amdgcn_mfma_f32_16x16x32_bf16(a[mi], b[ni], acc[mi][ni], 0, 0, 0);
    }
    for (int mi = 0; mi < 4; ++mi)
        for (int ni = 0; ni < 4; ++ni)
            for (int r = 0; r < 4; ++r) {
                int row = wm + mi * 16 + k8 * 4 + r;
                int cm = m0 + row;
                int d = n0 + wn + ni * 16 + l15;
                if (cm < CH) part[((size_t)ks * CH + cm) * 256 + d] = acc[mi][ni][r];
            }
}

// ---------------- REDUCE: out = query + bo + sum_ks part ---------------------------
__global__ __launch_bounds__(256) void k_reduce(
    const float* __restrict__ part, const float* __restrict__ query,
    const float* __restrict__ bo, float* __restrict__ out, int q0, int CH)
{
    int row = blockIdx.x, d = threadIdx.x;
    float s = bo[d] + query[(size_t)(q0 + row) * 256 + d];
    for (int ks = 0; ks < 8; ++ks) s += part[((size_t)ks * CH + row) * 256 + d];
    out[(size_t)(q0 + row) * 256 + d] = s;
}

extern "C" void kernel_launch(void* const* d_in, const int* in_sizes, int n_in,
                              void* d_out, int out_size, void* d_ws, size_t ws_size,
                              hipStream_t stream) {
    const float* x     = (const float*)d_in[0];
    const float* query = (const float*)d_in[1];
    const float* Wp    = (const float*)d_in[2];
    const float* bp    = (const float*)d_in[3];
    const float* Wo    = (const float*)d_in[4];
    const float* bo    = (const float*)d_in[5];
    float* out = (float*)d_out;

    char* ws = (char*)d_ws;
    unsigned short* Wpb = (unsigned short*)ws;                     // 16,777,216 B
    unsigned short* Wob = (unsigned short*)(ws + 16777216);        // 16,777,216 B
    unsigned short* qb  = (unsigned short*)(ws + 33554432);        //  2,048,000 B
    float*          bpp = (float*)(ws + 35602432);                 //    131,072 B
    char* chunkbase = ws + 35733504;
    const size_t fixed = 35733504;

    static const int cands[] = {4000, 2000, 1000, 500, 250, 125, 100, 50, 25, 20, 10, 8, 5, 4, 2, 1};
    int CH = 1;
    for (int i = 0; i < (int)(sizeof(cands) / sizeof(cands[0])); ++i) {
        size_t need = fixed + (size_t)cands[i] * (65536 + 8192);
        if (need <= ws_size) { CH = cands[i]; break; }
    }
    unsigned short* pm = (unsigned short*)chunkbase;
    float* part = (float*)(chunkbase + (size_t)CH * 65536);
    const int NC = 4000 / CH;

    k_perm_bp<<<128, 256, 0, stream>>>(bp, bpp);
    k_cvt_wp<<<2048, 256, 0, stream>>>(Wp, Wpb, 32768 * 256 / 4);
    k_cvt<<<2048, 256, 0, stream>>>(Wo, Wob, 256 * 32768 / 4);
    k_cvt<<<1000, 256, 0, stream>>>(query, qb, 4000 * 256 / 4);

    for (int c = 0; c < NC; ++c) {
        int q0 = c * CH;
        k_gemm1<<<dim3(256, (CH + 127) / 128), 256, 0, stream>>>(
            qb + (size_t)q0 * 256, Wpb, bpp, pm, CH);
        k_mix<<<dim3(4, CH), 256, 0, stream>>>(x, pm, q0);
        k_gemm2<<<dim3(2, (CH + 127) / 128, 8), 256, 0, stream>>>(pm, Wob, part, CH);
        k_reduce<<<dim3(CH), 256, 0, stream>>>(part, query, bo, out, q0, CH);
    }
}